// Round 7
// baseline (88.864 us; speedup 1.0000x reference)
//
#include <hip/hip_runtime.h>
#include <stdint.h>

// DeformConv1d: x[8,256,4096] f32, offsets[8,1,4094,3] f32,
// weight[256,256,3] f32, bias[256] f32 -> out[8,256,4094] f32.
//
// R7: attack the HBM write-RMW storm (R6: WRITE_SIZE 97MB vs 33.5MB output,
// dur == hbm_bytes/1.48TB/s, parallelism-insensitive).
//  (a) LDS-staged epilogue: acc -> padded f32 LDS tile (8 passes x 32 rows),
//      then contiguous 512B row-segment stores (lane-dwordx4).
//  (b) XCD-chunked decode b=bid&7, tt=bid>>3: all t-tiles of a batch share
//      an XCD so segment-boundary sectors merge in one L2.
// Compute loop is R5's proven transposed-window bf16 MFMA GEMM, BN=128.

constexpr int CIN  = 256;
constexpr int LX   = 4096;
constexpr int KT   = 3;
constexpr int OUTL = 4094;
constexpr int COUT = 256;
constexpr int BN   = 128;   // t per block
constexpr int WPOS = 132;   // window positions staged (t0 .. t0+131)
constexpr int NQ   = 24;    // K-chunks of 32 (2 c-halves x 3 taps x 4 c-subtiles)
constexpr int EPIW = 132;   // padded epilogue row (floats)

typedef __attribute__((ext_vector_type(8))) short bf16x8;
typedef __attribute__((ext_vector_type(4))) float f32x4;

__device__ __forceinline__ short f2bf(float f) {        // round-half-up
  union { float f; uint32_t u; } v; v.f = f;
  return (short)((v.u + 0x8000u) >> 16);
}
__device__ __forceinline__ uint32_t pack_bf2(float flo, float fhi) {
  union { float f; uint32_t u; } a, b; a.f = flo; b.f = fhi;
  return ((a.u + 0x8000u) >> 16) | ((b.u + 0x8000u) & 0xFFFF0000u);
}
__device__ __forceinline__ float bf2f(short s) {
  union { uint32_t u; float f; } v;
  v.u = ((uint32_t)(uint16_t)s) << 16;
  return v.f;
}

// Apack[q][o][k'] with q = ch*12 + ks, ks -> (ktap=ks>>2, csub=ks&3),
// k' = 0..31 covering c = ch*128 + csub*32 + k'.  24*256*32 shorts = 384 KB.
__global__ __launch_bounds__(256) void pack_weights_kernel(
    const float* __restrict__ w, short* __restrict__ ap) {
  const int idx = blockIdx.x * 256 + threadIdx.x;   // one u32 = 2 shorts
  if (idx >= NQ * COUT * 32 / 2) return;
  const int s    = idx * 2;
  const int kp   = s & 31;
  const int o    = (s >> 5) & 255;
  const int q    = s >> 13;
  const int ch   = q / 12;
  const int ks   = q % 12;
  const int ktap = ks >> 2;
  const int c0   = ch * 128 + (ks & 3) * 32;
  const float f0 = w[((size_t)o * CIN + c0 + kp) * KT + ktap];
  const float f1 = w[((size_t)o * CIN + c0 + kp + 1) * KT + ktap];
  *(uint32_t*)&ap[s] = pack_bf2(f0, f1);
}

__global__ __launch_bounds__(1024, 4) void deform_gemm_kernel(
    const float* __restrict__ x, const float* __restrict__ off,
    const short* __restrict__ ap, const float* __restrict__ bias,
    float* __restrict__ out) {

  // shared buffer: Xt (transposed x window, shorts) during compute,
  // Epi (f32 out staging, 32 x EPIW) during epilogue. 33792 B.
  __shared__ __align__(16) char smemBuf[WPOS * 128 * 2];
  __shared__ float biasS[COUT];    // 1024 B
  short* Xt  = (short*)smemBuf;
  float* Epi = (float*)smemBuf;    // needs 32*132*4 = 16896 B <= 33792

  const int tid  = threadIdx.x;
  const int lane = tid & 63;
  const int wid  = tid >> 6;       // 0..15
  const int llo  = lane & 15;
  const int lhi  = lane >> 4;

  // XCD-chunked decode: same batch -> same XCD (round-robin dispatch)
  const int b  = blockIdx.x & 7;    // 8 batches
  const int tt = blockIdx.x >> 3;   // 32 t-tiles
  const int t0 = tt * BN;

  const int wm = (wid >> 3) * 128;  // 2 wave-rows in M (128 rows each)
  const int wn = (wid & 7) * 16;    // 8 wave-cols in N (16 t each)

  // ---- per-lane interp meta in registers (statically indexed) ----
  float w0r[3], w1r[3];
  int   d0r[3];
  {
    const int t = t0 + wn + llo;
    #pragma unroll
    for (int k = 0; k < KT; ++k) {
      float w0 = 0.f, w1 = 0.f; int d0 = 0;
      if (t < OUTL) {
        const float o = off[((size_t)b * OUTL + t) * KT + k];
        float T = (float)(t + k) + o;
        T = fminf(fmaxf(T, (float)t), (float)(t + 2));  // clip to [t, t+2]
        int U0 = (int)T;                                 // floor (T >= 0)
        if (U0 > LX - 2) U0 = LX - 2;
        w1 = T - (float)U0;                              // in [0,1]
        w0 = 1.f - w1;
        d0 = U0 - t0;                                    // in [0, 130]
      }
      w0r[k] = w0; w1r[k] = w1; d0r[k] = d0;
    }
  }
  if (tid < COUT) biasS[tid] = bias[tid];

  f32x4 acc[8];
  #pragma unroll
  for (int i = 0; i < 8; ++i) acc[i] = (f32x4){0.f, 0.f, 0.f, 0.f};

  const float* xb = x + (size_t)b * CIN * LX;

  #pragma unroll
  for (int ch = 0; ch < 2; ++ch) {            // c-halves: [0,128) and [128,256)
    if (ch) __syncthreads();                  // previous half's K-steps done
    // ---- stage x window half, transposed ----
    #pragma unroll
    for (int rep = 0; rep < 17; ++rep) {
      const int idx = rep * 1024 + tid;
      if (idx < 128 * WPOS) {
        const int c   = idx / WPOS;
        const int pos = idx - c * WPOS;
        const int l   = t0 + pos;
        const float f = (l < LX) ? xb[(size_t)(ch * 128 + c) * LX + l] : 0.f;
        const int wi  = (pos * 128 + c) ^ ((pos & 7) << 3);
        Xt[wi] = f2bf(f);
      }
    }
    __syncthreads();  // window (and bias on first pass) visible

    #pragma unroll
    for (int ks = 0; ks < 12; ++ks) {         // NO barriers in here
      const int q    = ch * 12 + ks;
      const int ktap = ks >> 2;               // static -> meta stays in regs
      const int c0l  = (ks & 3) * 32;

      // ---- B fragment: 2 x ds_read_b128 from the transposed window ----
      const float w0 = w0r[ktap];
      const float w1 = w1r[ktap];
      const int   d0 = d0r[ktap];
      const int   cb = c0l + 8 * lhi;               // multiple of 8
      const int   i0 = (d0 * 128 + cb) ^ ((d0 & 7) << 3);
      const int   i1 = ((d0 + 1) * 128 + cb) ^ (((d0 + 1) & 7) << 3);
      const bf16x8 r0 = *(const bf16x8*)&Xt[i0];
      const bf16x8 r1 = *(const bf16x8*)&Xt[i1];
      bf16x8 bfr;
      #pragma unroll
      for (int j = 0; j < 8; ++j) {
        bfr[j] = f2bf(bf2f(r0[j]) * w0 + bf2f(r1[j]) * w1);
      }

      // ---- A fragments straight from L1/L2-hot packed weights ----
      const short* apq = ap + (((size_t)q * COUT + wm) << 5) + (lhi << 3);
      #pragma unroll
      for (int i = 0; i < 8; ++i) {
        const bf16x8 afr = *(const bf16x8*)(apq + (size_t)(i * 16 + llo) * 32);
        acc[i] = __builtin_amdgcn_mfma_f32_16x16x32_bf16(afr, bfr, acc[i], 0, 0, 0);
      }
    }
  }

  // ---- epilogue: LDS-staged, contiguous 512B row-segment stores ----
  // 8 passes of 32 rows. Producer: the 8 waves whose wm covers the rows
  // drain acc[i0], acc[i0+1] (+bias) into Epi[32][EPIW]. Consumer: all 16
  // waves store the 16KB tile as lane-contiguous dwordx4 (512B per row).
  const size_t obase = (size_t)b * COUT * OUTL;
  #pragma unroll
  for (int p = 0; p < 8; ++p) {
    __syncthreads();   // p==0: Xt->Epi reuse safe; else: prev consume done
    const int rbase = 32 * p;              // absolute row of this pass
    if (wm == (rbase & 128)) {             // producer waves
      const int i0 = (rbase & 127) >> 4;   // 2*(p%4)
      #pragma unroll
      for (int di = 0; di < 2; ++di) {
        const int i  = i0 + di;
        const int lr = 16 * di + 4 * lhi;  // local row 0..31 (plus r)
        const int row = wm + 16 * i + 4 * lhi;
        #pragma unroll
        for (int r = 0; r < 4; ++r) {
          Epi[(lr + r) * EPIW + wn + llo] = acc[i][r] + biasS[row + r];
        }
      }
    }
    __syncthreads();
    // consumer: flat 16B chunks; rr = row in pass, cc = t offset (floats)
    const int flat = tid;                  // 0..1023
    const int rr   = flat >> 5;            // 0..31
    const int cc   = (flat & 31) * 4;      // 0..124
    const f32x4 v  = *(const f32x4*)&Epi[rr * EPIW + cc];
    const int   t  = t0 + cc;
    float* op = out + obase + (size_t)(rbase + rr) * OUTL + t;
    if (t + 3 < OUTL) {
      *(f32x4*)op = v;
    } else {
      #pragma unroll
      for (int e = 0; e < 4; ++e)
        if (t + e < OUTL) op[e] = v[e];
    }
  }
}

extern "C" void kernel_launch(void* const* d_in, const int* in_sizes, int n_in,
                              void* d_out, int out_size, void* d_ws, size_t ws_size,
                              hipStream_t stream) {
  const float* x    = (const float*)d_in[0];
  const float* off  = (const float*)d_in[1];
  const float* wgt  = (const float*)d_in[2];
  const float* bias = (const float*)d_in[3];
  float* out  = (float*)d_out;
  short* ap   = (short*)d_ws;   // 24*256*32*2 = 393216 B of scratch

  // pack weights (runs each call; deterministic, ~3 us)
  pack_weights_kernel<<<dim3((NQ * COUT * 32 / 2 + 255) / 256), dim3(256), 0, stream>>>(wgt, ap);
  // 8 batches x 32 t-tiles = 256 blocks, 1024 threads (16 waves)
  deform_gemm_kernel<<<dim3(256), dim3(1024), 0, stream>>>(x, off, ap, bias, out);
}

// Round 9
// 76.148 us; speedup vs baseline: 1.1670x; 1.1670x over previous
//
#include <hip/hip_runtime.h>
#include <stdint.h>

// DeformConv1d: x[8,256,4096] f32, offsets[8,1,4094,3] f32,
// weight[256,256,3] f32, bias[256] f32 -> out[8,256,4094] f32.
//
// R9: R8's rolled-loop (I$-sized) body with the B-index bug fixed.
// R8 hoisted the XOR swizzle out of the csub loop as an ADD; when
// (d0&4)!=0 and csub odd the add carried into bit 6 -> wrong granule.
// Reverted to R7's proven per-iteration full XOR. Everything else
// identical to R8: ch/csub/staging loops rolled (#pragma unroll 1),
// ktap/MFMA/epilogue unrolled. Tests the I$-thrash theory cleanly vs R7.

constexpr int CIN  = 256;
constexpr int LX   = 4096;
constexpr int KT   = 3;
constexpr int OUTL = 4094;
constexpr int COUT = 256;
constexpr int BN   = 128;   // t per block
constexpr int WPOS = 132;   // window positions staged (t0 .. t0+131)
constexpr int NQ   = 24;    // K-chunks of 32 (2 c-halves x 3 taps x 4 c-subtiles)
constexpr int EPIW = 132;   // padded epilogue row (floats)

typedef __attribute__((ext_vector_type(8))) short bf16x8;
typedef __attribute__((ext_vector_type(4))) float f32x4;

__device__ __forceinline__ short f2bf(float f) {        // round-half-up
  union { float f; uint32_t u; } v; v.f = f;
  return (short)((v.u + 0x8000u) >> 16);
}
__device__ __forceinline__ uint32_t pack_bf2(float flo, float fhi) {
  union { float f; uint32_t u; } a, b; a.f = flo; b.f = fhi;
  return ((a.u + 0x8000u) >> 16) | ((b.u + 0x8000u) & 0xFFFF0000u);
}
__device__ __forceinline__ float bf2f(short s) {
  union { uint32_t u; float f; } v;
  v.u = ((uint32_t)(uint16_t)s) << 16;
  return v.f;
}

// Apack[q][o][k'] with q = ch*12 + ktap*4 + csub,
// k' = 0..31 covering c = ch*128 + csub*32 + k'.  24*256*32 shorts = 384 KB.
__global__ __launch_bounds__(256) void pack_weights_kernel(
    const float* __restrict__ w, short* __restrict__ ap) {
  const int idx = blockIdx.x * 256 + threadIdx.x;   // one u32 = 2 shorts
  if (idx >= NQ * COUT * 32 / 2) return;
  const int s    = idx * 2;
  const int kp   = s & 31;
  const int o    = (s >> 5) & 255;
  const int q    = s >> 13;
  const int ch   = q / 12;
  const int ks   = q % 12;
  const int ktap = ks >> 2;
  const int c0   = ch * 128 + (ks & 3) * 32;
  const float f0 = w[((size_t)o * CIN + c0 + kp) * KT + ktap];
  const float f1 = w[((size_t)o * CIN + c0 + kp + 1) * KT + ktap];
  *(uint32_t*)&ap[s] = pack_bf2(f0, f1);
}

__global__ __launch_bounds__(1024, 4) void deform_gemm_kernel(
    const float* __restrict__ x, const float* __restrict__ off,
    const short* __restrict__ ap, const float* __restrict__ bias,
    float* __restrict__ out) {

  // shared buffer: Xt (transposed x window, shorts) during compute,
  // Epi (f32 out staging, 32 x EPIW) during epilogue. 33792 B.
  __shared__ __align__(16) char smemBuf[WPOS * 128 * 2];
  __shared__ float biasS[COUT];    // 1024 B
  short* Xt  = (short*)smemBuf;
  float* Epi = (float*)smemBuf;    // needs 32*132*4 = 16896 B <= 33792

  const int tid  = threadIdx.x;
  const int lane = tid & 63;
  const int wid  = tid >> 6;       // 0..15
  const int llo  = lane & 15;
  const int lhi  = lane >> 4;

  // XCD-chunked decode: same batch -> same XCD (round-robin dispatch)
  const int b  = blockIdx.x & 7;    // 8 batches
  const int tt = blockIdx.x >> 3;   // 32 t-tiles
  const int t0 = tt * BN;

  const int wm = (wid >> 3) * 128;  // 2 wave-rows in M (128 rows each)
  const int wn = (wid & 7) * 16;    // 8 wave-cols in N (16 t each)

  // ---- per-lane interp meta in registers (statically indexed) ----
  float w0r[3], w1r[3];
  int   d0r[3];
  {
    const int t = t0 + wn + llo;
    #pragma unroll
    for (int k = 0; k < KT; ++k) {
      float w0 = 0.f, w1 = 0.f; int d0 = 0;
      if (t < OUTL) {
        const float o = off[((size_t)b * OUTL + t) * KT + k];
        float T = (float)(t + k) + o;
        T = fminf(fmaxf(T, (float)t), (float)(t + 2));  // clip to [t, t+2]
        int U0 = (int)T;                                 // floor (T >= 0)
        if (U0 > LX - 2) U0 = LX - 2;
        w1 = T - (float)U0;                              // in [0,1]
        w0 = 1.f - w1;
        d0 = U0 - t0;                                    // in [0, 130]
      }
      w0r[k] = w0; w1r[k] = w1; d0r[k] = d0;
    }
  }
  if (tid < COUT) biasS[tid] = bias[tid];

  f32x4 acc[8];
  #pragma unroll
  for (int i = 0; i < 8; ++i) acc[i] = (f32x4){0.f, 0.f, 0.f, 0.f};

  const float* xb = x + (size_t)b * CIN * LX;

  #pragma unroll 1
  for (int ch = 0; ch < 2; ++ch) {            // c-halves (ROLLED)
    if (ch) __syncthreads();                  // previous half's K-steps done
    // ---- stage x window half, transposed (ROLLED, small body) ----
    #pragma unroll 1
    for (int rep = 0; rep < 17; ++rep) {
      const int idx = rep * 1024 + tid;
      if (idx < 128 * WPOS) {
        const int c   = idx / WPOS;
        const int pos = idx - c * WPOS;
        const int l   = t0 + pos;
        const float f = (l < LX) ? xb[(size_t)(ch * 128 + c) * LX + l] : 0.f;
        const int wi  = (pos * 128 + c) ^ ((pos & 7) << 3);
        Xt[wi] = f2bf(f);
      }
    }
    __syncthreads();  // window (and bias on first pass) visible

    const short* apch = ap + ((size_t)ch * 12 * COUT + wm) * 32 + (lhi << 3);

    #pragma unroll
    for (int ktap = 0; ktap < KT; ++ktap) {   // UNROLLED: static meta index
      const float w0 = w0r[ktap];
      const float w1 = w1r[ktap];
      const int   d0 = d0r[ktap];
      const int   x0sw = (d0 & 7) << 3;        // swizzle terms (bits 3..5)
      const int   x1sw = ((d0 + 1) & 7) << 3;
      const int   row0 = d0 * 128;
      const int   row1 = (d0 + 1) * 128;
      const short* aptr = apch + (size_t)ktap * 4 * COUT * 32;

      #pragma unroll 1
      for (int csub = 0; csub < 4; ++csub) {  // ROLLED: keeps body small
        const int cb = csub * 32 + 8 * lhi;
        // full XOR per iteration (R7's proven form — no carry hazard)
        const int i0 = (row0 + cb) ^ x0sw;
        const int i1 = (row1 + cb) ^ x1sw;
        const bf16x8 r0 = *(const bf16x8*)&Xt[i0];
        const bf16x8 r1 = *(const bf16x8*)&Xt[i1];
        bf16x8 bfr;
        #pragma unroll
        for (int j = 0; j < 8; ++j) {
          bfr[j] = f2bf(bf2f(r0[j]) * w0 + bf2f(r1[j]) * w1);
        }
        // ---- A fragments from L1/L2-hot packed weights ----
        const short* apq = aptr + (size_t)csub * COUT * 32;
        #pragma unroll
        for (int i = 0; i < 8; ++i) {
          const bf16x8 afr = *(const bf16x8*)(apq + (size_t)(i * 16 + llo) * 32);
          acc[i] = __builtin_amdgcn_mfma_f32_16x16x32_bf16(afr, bfr, acc[i], 0, 0, 0);
        }
      }
    }
  }

  // ---- epilogue: LDS-staged, contiguous 512B row-segment stores ----
  // (p-loop UNROLLED: acc index must stay static — rule #20)
  const size_t obase = (size_t)b * COUT * OUTL;
  #pragma unroll
  for (int p = 0; p < 8; ++p) {
    __syncthreads();   // p==0: Xt->Epi reuse safe; else: prev consume done
    const int rbase = 32 * p;              // absolute row of this pass
    if (wm == (rbase & 128)) {             // producer waves
      const int i0 = (rbase & 127) >> 4;
      #pragma unroll
      for (int di = 0; di < 2; ++di) {
        const int i  = i0 + di;
        const int lr = 16 * di + 4 * lhi;  // local row 0..31 (plus r)
        const int row = wm + 16 * i + 4 * lhi;
        #pragma unroll
        for (int r = 0; r < 4; ++r) {
          Epi[(lr + r) * EPIW + wn + llo] = acc[i][r] + biasS[row + r];
        }
      }
    }
    __syncthreads();
    // consumer: flat 16B chunks; rr = row in pass, cc = t offset (floats)
    const int rr = tid >> 5;               // 0..31
    const int cc = (tid & 31) * 4;         // 0..124
    const f32x4 v = *(const f32x4*)&Epi[rr * EPIW + cc];
    const int   t = t0 + cc;
    float* op = out + obase + (size_t)(rbase + rr) * OUTL + t;
    if (t + 3 < OUTL) {
      *(f32x4*)op = v;
    } else {
      #pragma unroll
      for (int e = 0; e < 4; ++e)
        if (t + e < OUTL) op[e] = v[e];
    }
  }
}

extern "C" void kernel_launch(void* const* d_in, const int* in_sizes, int n_in,
                              void* d_out, int out_size, void* d_ws, size_t ws_size,
                              hipStream_t stream) {
  const float* x    = (const float*)d_in[0];
  const float* off  = (const float*)d_in[1];
  const float* wgt  = (const float*)d_in[2];
  const float* bias = (const float*)d_in[3];
  float* out  = (float*)d_out;
  short* ap   = (short*)d_ws;   // 24*256*32*2 = 393216 B of scratch

  // pack weights (runs each call; deterministic, ~3 us)
  pack_weights_kernel<<<dim3((NQ * COUT * 32 / 2 + 255) / 256), dim3(256), 0, stream>>>(wgt, ap);
  // 8 batches x 32 t-tiles = 256 blocks, 1024 threads (16 waves)
  deform_gemm_kernel<<<dim3(256), dim3(1024), 0, stream>>>(x, off, ap, bias, out);
}

// Round 10
// 61.590 us; speedup vs baseline: 1.4428x; 1.2364x over previous
//
#include <hip/hip_runtime.h>
#include <stdint.h>

// DeformConv1d: x[8,256,4096] f32, offsets[8,1,4094,3] f32,
// weight[256,256,3] f32, bias[256] f32 -> out[8,256,4094] f32.
//
// R10: stage A through LDS (m97 2-barrier K-step). R9 streamed A frags
// from global per MFMA: 3MB/CU L1 traffic (8x duplicate) + all 256 CUs
// sweeping the same ap region in lockstep (L2 slice hotspot). Now each
// 16KB A-tile is loaded ONCE per block (reg-staged, coalesced, issued
// before the B-build so L2 latency hides under it), all waves ds_read
// fragments. 8 waves = 2M x 4N x 2 N-frags, BN=128, acc[8][2].
// Keeps: transposed swizzled Xt window, register meta, rolled loops (I$),
// LDS epilogue (WRITE=33MB, keep), XCD-chunked decode.

constexpr int CIN  = 256;
constexpr int LX   = 4096;
constexpr int KT   = 3;
constexpr int OUTL = 4094;
constexpr int COUT = 256;
constexpr int BN   = 128;   // t per block
constexpr int WPOS = 132;   // window positions staged (t0 .. t0+131)
constexpr int NQ   = 24;    // K-chunks of 32 (2 c-halves x 3 taps x 4 c-subtiles)
constexpr int EPIW = 132;   // padded epilogue row (floats)

typedef __attribute__((ext_vector_type(8))) short bf16x8;
typedef __attribute__((ext_vector_type(4))) float f32x4;

__device__ __forceinline__ short f2bf(float f) {        // round-half-up
  union { float f; uint32_t u; } v; v.f = f;
  return (short)((v.u + 0x8000u) >> 16);
}
__device__ __forceinline__ uint32_t pack_bf2(float flo, float fhi) {
  union { float f; uint32_t u; } a, b; a.f = flo; b.f = fhi;
  return ((a.u + 0x8000u) >> 16) | ((b.u + 0x8000u) & 0xFFFF0000u);
}
__device__ __forceinline__ float bf2f(short s) {
  union { uint32_t u; float f; } v;
  v.u = ((uint32_t)(uint16_t)s) << 16;
  return v.f;
}

// Apack[q][o][k'] with q = ch*12 + ktap*4 + csub,
// k' = 0..31 covering c = ch*128 + csub*32 + k'.  24*256*32 shorts = 384 KB.
__global__ __launch_bounds__(256) void pack_weights_kernel(
    const float* __restrict__ w, short* __restrict__ ap) {
  const int idx = blockIdx.x * 256 + threadIdx.x;   // one u32 = 2 shorts
  if (idx >= NQ * COUT * 32 / 2) return;
  const int s    = idx * 2;
  const int kp   = s & 31;
  const int o    = (s >> 5) & 255;
  const int q    = s >> 13;
  const int ch   = q / 12;
  const int ks   = q % 12;
  const int ktap = ks >> 2;
  const int c0   = ch * 128 + (ks & 3) * 32;
  const float f0 = w[((size_t)o * CIN + c0 + kp) * KT + ktap];
  const float f1 = w[((size_t)o * CIN + c0 + kp + 1) * KT + ktap];
  *(uint32_t*)&ap[s] = pack_bf2(f0, f1);
}

__global__ __launch_bounds__(512, 2) void deform_gemm_kernel(
    const float* __restrict__ x, const float* __restrict__ off,
    const short* __restrict__ ap, const float* __restrict__ bias,
    float* __restrict__ out) {

  // arena: [0,33792) Xt (transposed window) / Epi (epilogue f32 reuse),
  //        [33792, 50176) As (A tile, 256x32 bf16), [50176, 51200) biasS
  __shared__ __align__(16) char smem[33792 + 16384 + 1024];
  short* Xt    = (short*)smem;
  short* As    = (short*)(smem + 33792);
  float* Epi   = (float*)smem;
  float* biasS = (float*)(smem + 33792 + 16384);

  const int tid  = threadIdx.x;
  const int lane = tid & 63;
  const int wid  = tid >> 6;       // 0..7
  const int llo  = lane & 15;
  const int lhi  = lane >> 4;

  // XCD-chunked decode: same batch -> same XCD (round-robin dispatch)
  const int b  = blockIdx.x & 7;    // 8 batches
  const int tt = blockIdx.x >> 3;   // 32 t-tiles
  const int t0 = tt * BN;

  const int wm = (wid >> 2) * 128;  // 2 wave-rows in M (128 rows each)
  const int wn = (wid & 3) * 32;    // 4 wave-cols in N (32 t each, 2 frags)

  // ---- per-lane interp meta in registers (statically indexed) ----
  float w0r[2][3], w1r[2][3];
  int   d0r[2][3];
  #pragma unroll
  for (int jn = 0; jn < 2; ++jn) {
    const int t = t0 + wn + jn * 16 + llo;
    #pragma unroll
    for (int k = 0; k < KT; ++k) {
      float w0 = 0.f, w1 = 0.f; int d0 = 0;
      if (t < OUTL) {
        const float o = off[((size_t)b * OUTL + t) * KT + k];
        float T = (float)(t + k) + o;
        T = fminf(fmaxf(T, (float)t), (float)(t + 2));  // clip to [t, t+2]
        int U0 = (int)T;                                 // floor (T >= 0)
        if (U0 > LX - 2) U0 = LX - 2;
        w1 = T - (float)U0;                              // in [0,1]
        w0 = 1.f - w1;
        d0 = U0 - t0;                                    // in [0, 130]
      }
      w0r[jn][k] = w0; w1r[jn][k] = w1; d0r[jn][k] = d0;
    }
  }
  if (tid < COUT) biasS[tid] = bias[tid];

  f32x4 acc[8][2];
  #pragma unroll
  for (int i = 0; i < 8; ++i) {
    acc[i][0] = (f32x4){0.f, 0.f, 0.f, 0.f};
    acc[i][1] = (f32x4){0.f, 0.f, 0.f, 0.f};
  }

  const float* xb = x + (size_t)b * CIN * LX;

  #pragma unroll 1
  for (int ch = 0; ch < 2; ++ch) {            // c-halves (ROLLED)
    if (ch) __syncthreads();                  // prev half's Xt consumers done
    // ---- stage x window half, transposed (ROLLED) ----
    // 128*132 = 16896 = 33 * 512 exactly.
    #pragma unroll 1
    for (int rep = 0; rep < 33; ++rep) {
      const int idx = rep * 512 + tid;
      const int c   = idx / WPOS;
      const int pos = idx - c * WPOS;
      const int l   = t0 + pos;
      const float f = (l < LX) ? xb[(size_t)(ch * 128 + c) * LX + l] : 0.f;
      const int wi  = (pos * 128 + c) ^ ((pos & 7) << 3);
      Xt[wi] = f2bf(f);
    }
    __syncthreads();  // window (and bias on first pass) visible

    #pragma unroll
    for (int ktap = 0; ktap < KT; ++ktap) {   // UNROLLED: static meta index
      const int   x0sw = (d0r[0][ktap] & 7) << 3;   // (frag-0 d0)
      #pragma unroll 1
      for (int csub = 0; csub < 4; ++csub) {  // ROLLED: small I$ body
        // ---- A stage: global (L2-hot packed) -> regs, issued FIRST ----
        const short* apq = ap + (((size_t)(ch * 12 + ktap * 4 + csub)) << 13);
        const bf16x8 a0 = *(const bf16x8*)(apq + tid * 8);
        const bf16x8 a1 = *(const bf16x8*)(apq + 4096 + tid * 8);

        // ---- B fragments from Xt (hides the A-load latency) ----
        bf16x8 bfr[2];
        #pragma unroll
        for (int jn = 0; jn < 2; ++jn) {
          const float w0 = w0r[jn][ktap];
          const float w1 = w1r[jn][ktap];
          const int   d0 = d0r[jn][ktap];
          const int   cb = csub * 32 + 8 * lhi;
          const int   i0 = (d0 * 128 + cb) ^ ((d0 & 7) << 3);
          const int   i1 = ((d0 + 1) * 128 + cb) ^ (((d0 + 1) & 7) << 3);
          const bf16x8 r0 = *(const bf16x8*)&Xt[i0];
          const bf16x8 r1 = *(const bf16x8*)&Xt[i1];
          #pragma unroll
          for (int j = 0; j < 8; ++j) {
            bfr[jn][j] = f2bf(bf2f(r0[j]) * w0 + bf2f(r1[j]) * w1);
          }
        }

        // ---- A regs -> LDS (prev step's readers done: trailing barrier) ----
        *(bf16x8*)(As + tid * 8) = a0;
        *(bf16x8*)(As + 4096 + tid * 8) = a1;
        __syncthreads();   // As staged, visible to all

        // ---- MFMA: 8 m-frags x 2 n-frags, A from LDS ----
        #pragma unroll
        for (int i = 0; i < 8; ++i) {
          const bf16x8 afr = *(const bf16x8*)(As + (wm + i * 16 + llo) * 32 + lhi * 8);
          acc[i][0] = __builtin_amdgcn_mfma_f32_16x16x32_bf16(afr, bfr[0], acc[i][0], 0, 0, 0);
          acc[i][1] = __builtin_amdgcn_mfma_f32_16x16x32_bf16(afr, bfr[1], acc[i][1], 0, 0, 0);
        }
        __syncthreads();   // all reads of As done before next stage
        (void)x0sw;
      }
    }
  }

  // ---- epilogue: LDS-staged, contiguous row-segment stores ----
  // (p-loop UNROLLED: acc index must stay static — rule #20)
  const size_t obase = (size_t)b * COUT * OUTL;
  #pragma unroll
  for (int p = 0; p < 8; ++p) {
    __syncthreads();   // p==0: Xt->Epi reuse safe; else: prev consume done
    const int rbase = 32 * p;              // absolute row of this pass
    if (wm == (rbase & 128)) {             // 4 producer waves
      const int i0 = (rbase & 127) >> 4;
      #pragma unroll
      for (int di = 0; di < 2; ++di) {
        const int i  = i0 + di;
        const int lr = 16 * di + 4 * lhi;  // local row 0..31 (plus r)
        #pragma unroll
        for (int jn = 0; jn < 2; ++jn) {
          const int col = wn + jn * 16 + llo;
          #pragma unroll
          for (int r = 0; r < 4; ++r) {
            Epi[(lr + r) * EPIW + col] = acc[i][jn][r] + biasS[rbase + lr + r];
          }
        }
      }
    }
    __syncthreads();
    // consumer: 512 threads, 32 x 128 f32 tile; 32B per thread
    const int rr = tid >> 4;               // 0..31
    const int c8 = (tid & 15) * 8;         // 0..120
    float* op = out + obase + (size_t)(rbase + rr) * OUTL + t0 + c8;
    #pragma unroll
    for (int j2 = 0; j2 < 2; ++j2) {
      const f32x4 v = *(const f32x4*)&Epi[rr * EPIW + c8 + 4 * j2];
      const int   t = t0 + c8 + 4 * j2;
      if (t + 3 < OUTL) {
        *(f32x4*)(op + 4 * j2) = v;
      } else {
        #pragma unroll
        for (int e = 0; e < 4; ++e)
          if (t + e < OUTL) op[4 * j2 + e] = v[e];
      }
    }
  }
}

extern "C" void kernel_launch(void* const* d_in, const int* in_sizes, int n_in,
                              void* d_out, int out_size, void* d_ws, size_t ws_size,
                              hipStream_t stream) {
  const float* x    = (const float*)d_in[0];
  const float* off  = (const float*)d_in[1];
  const float* wgt  = (const float*)d_in[2];
  const float* bias = (const float*)d_in[3];
  float* out  = (float*)d_out;
  short* ap   = (short*)d_ws;   // 24*256*32*2 = 393216 B of scratch

  // pack weights (runs each call; deterministic, ~3 us)
  pack_weights_kernel<<<dim3((NQ * COUT * 32 / 2 + 255) / 256), dim3(256), 0, stream>>>(wgt, ap);
  // 8 batches x 32 t-tiles = 256 blocks, 512 threads (8 waves)
  deform_gemm_kernel<<<dim3(256), dim3(512), 0, stream>>>(x, off, ap, bias, out);
}